// Round 8
// baseline (45.424 us; speedup 1.0000x reference)
//
#include <hip/hip_runtime.h>

#define GRIDS 7
#define NCELL 49
#define NFEAT 25
#define CELLSZ 1225   // 49*25 floats per batch
#define BPB 16        // batches per block: 16*1225*4B = 78400 B slab, float4-aligned
#define MAXBOX 16
#define FIXSCALE 1048576.0   // 2^20 fixed-point scale for the cross-block sum

// Decomposition:
//   stream:   every cell contributes 0.5 * p_conf^2   (the noobj default)
//   correct:  each kept box's cell adds
//     f<2 : 5*(xo|yo - p)^2
//     f=2,3: 5*(sqrt(w|h) - sqrt(p))^2
//     f=4 : (1-p)^2 - 0.5*p^2     (replaces the streamed default)
//     f>=5: (onehot - p)^2
// Single kernel. Cross-block reduction is FENCE-FREE (round-5 lesson:
// threadfence + ACQ_REL per block = L2 writeback storms on non-coherent XCD
// L2s -> 91 us). Instead: relaxed agent-scope u64 fixed-point atomicAdd
// (native global_atomic_add_x2, coherent by construction, deterministic),
// ordered against the counter increment by a plain s_waitcnt vmcnt(0)
// (completion wait only, no cache maintenance).

__device__ __forceinline__ float conf_of(float4 v, unsigned e0) {
    // element e0+k is a conf lane iff (e0+k) % 25 == 4
    unsigned q = (e0 * 5243u) >> 17;   // e0/25, exact for e0 < 43690 (max here 19596)
    unsigned r = e0 - q * 25u;
    return (r == 4u) ? v.x : (r == 3u) ? v.y : (r == 2u) ? v.z
         : (r == 1u) ? v.w : 0.f;
}

__global__ __launch_bounds__(256) void yolo_fused(
    const float* __restrict__ pred, const float* __restrict__ bbox,
    unsigned long long* __restrict__ acc64, unsigned* __restrict__ counter,
    float* __restrict__ out, int B, int nbox, int nblocks)
{
    __shared__ float sBox[BPB * MAXBOX * 5];   // xo, yo, sqrt(w), sqrt(h), label
    __shared__ int   sOff[BPB * MAXBOX];       // element offset of box's cell in slab
    __shared__ int   sKeep[BPB * MAXBOX];
    __shared__ float sRed[4];

    const int tid = threadIdx.x;
    const long long b0 = (long long)blockIdx.x * BPB;
    const int nb = min(BPB, B - (int)b0);
    const int nbx = nb * nbox;                  // <= 256
    const int nelem = nb * CELLSZ;
    const int nvec  = nelem >> 2;               // 4900 for full blocks
    const float* pb = pred + b0 * CELLSZ;
    const float4* p4 = (const float4*)pb;

    // 0) Stream prefetch FIRST — memory pipe busy during the preamble.
    float4 pf0 = make_float4(0.f, 0.f, 0.f, 0.f), pf1 = pf0, pf2 = pf0, pf3 = pf0;
    if (tid       < nvec) pf0 = p4[tid];
    if (tid + 256 < nvec) pf1 = p4[tid + 256];
    if (tid + 512 < nvec) pf2 = p4[tid + 512];
    if (tid + 768 < nvec) pf3 = p4[tid + 768];

    // Preamble A: per-box derived values (f32 op order matches reference)
    if (tid < nbx) {
        const float* bx = bbox + (b0 * nbox + tid) * 5;
        float x1 = bx[0] / 448.f, y1 = bx[1] / 448.f;
        float x2 = bx[2] / 448.f, y2 = bx[3] / 448.f;
        float xc = (x1 + x2) * 0.5f, yc = (y1 + y2) * 0.5f;
        float w  = x2 - x1,          h  = y2 - y1;
        float xs = xc * (float)GRIDS, ys = yc * (float)GRIDS;
        float xg = floorf(xs), yg = floorf(ys);
        int lb = tid / nbox;
        int cell = (int)yg * GRIDS + (int)xg;
        sOff[tid] = lb * CELLSZ + cell * NFEAT;
        float* e = &sBox[tid * 5];
        e[0] = xs - xg; e[1] = ys - yg;
        e[2] = sqrtf(w); e[3] = sqrtf(h);
        e[4] = bx[4];
    }
    __syncthreads();

    // Preamble B: keep mask — first box claiming a cell (within its batch) wins.
    if (tid < nbx) {
        int lb = tid / nbox;
        int o  = sOff[tid];
        int k = 1;
        for (int j = lb * nbox; j < tid; ++j)
            if (sOff[j] == o) { k = 0; break; }
        sKeep[tid] = k;
    }
    __syncthreads();

    // 1) Correction gather ISSUE (hoisted): each 32-lane half-wave covers one
    //    box's 25 features. Latency hides under the stream loop below.
    const int wid = tid >> 6, lane = tid & 63;
    const int f = lane & 31;
    const int cbase = wid * 2 + (lane >> 5);    // 0..7
    float gv[16];
    #pragma unroll
    for (int k = 0; k < 16; ++k) {
        int bi = cbase + 8 * k;
        bool v = (bi < nbx) && (f < NFEAT) && sKeep[bi];
        gv[k] = v ? pb[sOff[bi] + f] : 0.f;
    }

    // 2) Streaming pass: 0.5*p^2 for the conf lane of each float4 group.
    float acc = 0.f;
    if (tid       < nvec) { float c = conf_of(pf0, (unsigned)tid << 2);         acc = fmaf(0.5f * c, c, acc); }
    if (tid + 256 < nvec) { float c = conf_of(pf1, (unsigned)(tid + 256) << 2); acc = fmaf(0.5f * c, c, acc); }
    if (tid + 512 < nvec) { float c = conf_of(pf2, (unsigned)(tid + 512) << 2); acc = fmaf(0.5f * c, c, acc); }
    if (tid + 768 < nvec) { float c = conf_of(pf3, (unsigned)(tid + 768) << 2); acc = fmaf(0.5f * c, c, acc); }

    int i = tid + 1024;
    for (; i + 768 < nvec; i += 1024) {
        float4 a = p4[i];
        float4 b = p4[i + 256];
        float4 c = p4[i + 512];
        float4 d = p4[i + 768];
        float ca = conf_of(a, (unsigned)i << 2);
        float cb = conf_of(b, (unsigned)(i + 256) << 2);
        float cc = conf_of(c, (unsigned)(i + 512) << 2);
        float cd = conf_of(d, (unsigned)(i + 768) << 2);
        acc = fmaf(0.5f * ca, ca, acc);
        acc = fmaf(0.5f * cb, cb, acc);
        acc = fmaf(0.5f * cc, cc, acc);
        acc = fmaf(0.5f * cd, cd, acc);
    }
    for (; i < nvec; i += 256) {
        float4 a = p4[i];
        float c = conf_of(a, (unsigned)i << 2);
        acc = fmaf(0.5f * c, c, acc);
    }
    for (int e = (nvec << 2) + tid; e < nelem; e += 256) {   // partial-block tail
        unsigned q = ((unsigned)e * 5243u) >> 17;
        if ((unsigned)e - q * 25u == 4u) {
            float p = pb[e];
            acc = fmaf(0.5f * p, p, acc);
        }
    }

    // 3) Correction consume (values already in registers)
    #pragma unroll
    for (int k = 0; k < 16; ++k) {
        int bi = cbase + 8 * k;
        bool v = (bi < nbx) && (f < NFEAT) && sKeep[bi];
        if (v) {
            const float* e = &sBox[bi * 5];
            float p = gv[k];
            float term;
            if (f == 4) {
                float d = 1.f - p;
                term = fmaf(d, d, -0.5f * p * p);
            } else if (f < 4) {
                float q = (f >= 2) ? sqrtf(p) : p;
                float d = e[f] - q;
                term = 5.f * d * d;
            } else {
                float t = ((int)e[4] == f - 5) ? 1.f : 0.f;
                float d = t - p;
                term = d * d;
            }
            acc += term;
        }
    }

    // 4) Deterministic block reduction
    for (int off = 32; off; off >>= 1)
        acc += __shfl_down(acc, off, 64);
    if ((tid & 63) == 0) sRed[tid >> 6] = acc;
    __syncthreads();

    // 5) Fence-free cross-block reduction (see header comment).
    if (tid == 0) {
        float bsum = sRed[0] + sRed[1] + sRed[2] + sRed[3];
        unsigned long long fx =
            (unsigned long long)__double2ll_rn((double)bsum * FIXSCALE);
        __hip_atomic_fetch_add(acc64, fx, __ATOMIC_RELAXED,
                               __HIP_MEMORY_SCOPE_AGENT);
        // Completion wait only (no cache maintenance): our add is globally
        // performed before our counter increment can be observed.
        asm volatile("s_waitcnt vmcnt(0)" ::: "memory");
        unsigned prev = __hip_atomic_fetch_add(counter, 1u, __ATOMIC_RELAXED,
                                               __HIP_MEMORY_SCOPE_AGENT);
        if (prev == (unsigned)(nblocks - 1)) {
            // All other increments precede ours; each was preceded by its
            // block's completed add -> a coherent load now sees the total.
            unsigned long long tot =
                __hip_atomic_load(acc64, __ATOMIC_RELAXED,
                                  __HIP_MEMORY_SCOPE_AGENT);
            out[0] = (float)(((double)(long long)tot / FIXSCALE) / (double)B);
        }
    }
}

extern "C" void kernel_launch(void* const* d_in, const int* in_sizes, int n_in,
                              void* d_out, int out_size, void* d_ws, size_t ws_size,
                              hipStream_t stream) {
    const float* pred = (const float*)d_in[0];
    const float* bbox = (const float*)d_in[1];
    int B = in_sizes[0] / CELLSZ;
    int nbox = in_sizes[1] / (B * 5);
    if (nbox > MAXBOX) nbox = MAXBOX;
    float* out = (float*)d_out;

    unsigned long long* acc64 = (unsigned long long*)d_ws;            // cacheline 0
    unsigned* counter = (unsigned*)((char*)d_ws + 64);                // cacheline 1

    int nblocks = (B + BPB - 1) / BPB;
    hipMemsetAsync(d_ws, 0, 128, stream);
    yolo_fused<<<nblocks, 256, 0, stream>>>(pred, bbox, acc64, counter, out,
                                            B, nbox, nblocks);
}

// Round 9
// 26.299 us; speedup vs baseline: 1.7272x; 1.7272x over previous
//
#include <hip/hip_runtime.h>

#define GRIDS 7
#define NCELL 49
#define NFEAT 25
#define CELLSZ 1225   // 49*25 floats per batch
#define BPB 16        // batches per block -> 1024 blocks at B=16384
#define MAXBOX 16

// Decomposition:
//   gather:   every cell contributes 0.5 * p_conf^2  (conf lane only — the
//             other 24/25 of pred are never needed for noobj cells)
//   correct:  each kept box's cell adds
//     f<2 : 5*(xo|yo - p)^2
//     f=2,3: 5*(sqrt(w|h) - sqrt(p))^2
//     f=4 : (1-p)^2 - 0.5*p^2     (replaces the gathered default)
//     f>=5: (onehot - p)^2
// Two kernels. Cross-block single-address combining is structurally bad on
// this chip (round 5: fences -> 91us; round 8: relaxed atomics -> 45us burst
// serialization with all blocks co-resident). Plain partial[] + tiny reduce
// kernel wins.

__global__ __launch_bounds__(256) void yolo_main(
    const float* __restrict__ pred, const float* __restrict__ bbox,
    float* __restrict__ partial, int B, int nbox)
{
    __shared__ float sBox[BPB * MAXBOX * 5];   // xo, yo, sqrt(w), sqrt(h), label
    __shared__ int   sOff[BPB * MAXBOX];       // element offset of box's cell in slab
    __shared__ int   sKeep[BPB * MAXBOX];
    __shared__ float sRed[4];

    const int tid = threadIdx.x;
    const long long b0 = (long long)blockIdx.x * BPB;
    const int nb = min(BPB, B - (int)b0);
    const int nbx = nb * nbox;                  // <= 256
    const float* pb = pred + b0 * CELLSZ;

    // 0) Conf-lane gather ISSUE — first instructions of the kernel, zero
    //    dependencies. ncells <= 784 -> at most 4 loads per thread, all in
    //    flight while the preamble runs. Element (lb,c) conf = pb[lb*1225+c*25+4].
    const int ncells = nb * NCELL;
    float cf0 = 0.f, cf1 = 0.f, cf2 = 0.f, cf3 = 0.f;
    {
        int t0 = tid, t1 = tid + 256, t2 = tid + 512, t3 = tid + 768;
        if (t0 < ncells) {
            unsigned lb = ((unsigned)t0 * 2676u) >> 17;           // t/49, exact t<~1500
            cf0 = pb[lb * CELLSZ + ((unsigned)t0 - lb * 49u) * NFEAT + 4];
        }
        if (t1 < ncells) {
            unsigned lb = ((unsigned)t1 * 2676u) >> 17;
            cf1 = pb[lb * CELLSZ + ((unsigned)t1 - lb * 49u) * NFEAT + 4];
        }
        if (t2 < ncells) {
            unsigned lb = ((unsigned)t2 * 2676u) >> 17;
            cf2 = pb[lb * CELLSZ + ((unsigned)t2 - lb * 49u) * NFEAT + 4];
        }
        if (t3 < ncells) {
            unsigned lb = ((unsigned)t3 * 2676u) >> 17;
            cf3 = pb[lb * CELLSZ + ((unsigned)t3 - lb * 49u) * NFEAT + 4];
        }
    }

    // Preamble A: per-box derived values (f32 op order matches reference)
    if (tid < nbx) {
        const float* bx = bbox + (b0 * nbox + tid) * 5;
        float x1 = bx[0] / 448.f, y1 = bx[1] / 448.f;
        float x2 = bx[2] / 448.f, y2 = bx[3] / 448.f;
        float xc = (x1 + x2) * 0.5f, yc = (y1 + y2) * 0.5f;
        float w  = x2 - x1,          h  = y2 - y1;
        float xs = xc * (float)GRIDS, ys = yc * (float)GRIDS;
        float xg = floorf(xs), yg = floorf(ys);
        int lb = tid / nbox;
        int cell = (int)yg * GRIDS + (int)xg;
        sOff[tid] = lb * CELLSZ + cell * NFEAT;
        float* e = &sBox[tid * 5];
        e[0] = xs - xg; e[1] = ys - yg;
        e[2] = sqrtf(w); e[3] = sqrtf(h);
        e[4] = bx[4];
    }
    __syncthreads();

    // Preamble B: keep mask — first box claiming a cell (within its batch) wins.
    if (tid < nbx) {
        int lb = tid / nbox;
        int o  = sOff[tid];
        int k = 1;
        for (int j = lb * nbox; j < tid; ++j)
            if (sOff[j] == o) { k = 0; break; }
        sKeep[tid] = k;
    }
    __syncthreads();

    // 1) Correction gather ISSUE (hoisted): each 32-lane half-wave covers one
    //    box's 25 features. Covers bi < 128 (nbx = 16*8 = 128 in this bench);
    //    guarded tail loop below handles any overflow.
    const int wid = tid >> 6, lane = tid & 63;
    const int f = lane & 31;
    const int cbase = wid * 2 + (lane >> 5);    // 0..7
    float gv[16];
    #pragma unroll
    for (int k = 0; k < 16; ++k) {
        int bi = cbase + 8 * k;
        bool v = (bi < nbx) && (f < NFEAT) && sKeep[bi];
        gv[k] = v ? pb[sOff[bi] + f] : 0.f;
    }

    // 2) Conf consume: 0.5*p^2
    float acc = 0.f;
    acc = fmaf(0.5f * cf0, cf0, acc);
    acc = fmaf(0.5f * cf1, cf1, acc);
    acc = fmaf(0.5f * cf2, cf2, acc);
    acc = fmaf(0.5f * cf3, cf3, acc);

    // 3) Correction consume
    #pragma unroll
    for (int k = 0; k < 16; ++k) {
        int bi = cbase + 8 * k;
        bool v = (bi < nbx) && (f < NFEAT) && sKeep[bi];
        if (v) {
            const float* e = &sBox[bi * 5];
            float p = gv[k];
            float term;
            if (f == 4) {
                float d = 1.f - p;
                term = fmaf(d, d, -0.5f * p * p);
            } else if (f < 4) {
                float q = (f >= 2) ? sqrtf(p) : p;
                float d = e[f] - q;
                term = 5.f * d * d;
            } else {
                float t = ((int)e[4] == f - 5) ? 1.f : 0.f;
                float d = t - p;
                term = d * d;
            }
            acc += term;
        }
    }
    // Safety tail: boxes beyond the hoisted window (never taken when nbx<=128)
    for (int bi = 128 + cbase; bi < nbx; bi += 8) {
        if (f < NFEAT && sKeep[bi]) {
            const float* e = &sBox[bi * 5];
            float p = pb[sOff[bi] + f];
            float term;
            if (f == 4) {
                float d = 1.f - p;
                term = fmaf(d, d, -0.5f * p * p);
            } else if (f < 4) {
                float q = (f >= 2) ? sqrtf(p) : p;
                float d = e[f] - q;
                term = 5.f * d * d;
            } else {
                float t = ((int)e[4] == f - 5) ? 1.f : 0.f;
                float d = t - p;
                term = d * d;
            }
            acc += term;
        }
    }

    // 4) Deterministic block reduction
    for (int off = 32; off; off >>= 1)
        acc += __shfl_down(acc, off, 64);
    if ((tid & 63) == 0) sRed[tid >> 6] = acc;
    __syncthreads();
    if (tid == 0)
        partial[blockIdx.x] = sRed[0] + sRed[1] + sRed[2] + sRed[3];
}

__global__ __launch_bounds__(256) void yolo_reduce(
    const float* __restrict__ partial, int n, float* __restrict__ out, int B)
{
    __shared__ double s[256];
    const float4* p4 = (const float4*)partial;
    const int n4 = n >> 2;
    double a = 0.0;
    for (int j = threadIdx.x; j < n4; j += 256) {
        float4 v = p4[j];
        a += (double)v.x + (double)v.y + (double)v.z + (double)v.w;
    }
    for (int j = (n4 << 2) + threadIdx.x; j < n; j += 256)
        a += (double)partial[j];
    s[threadIdx.x] = a;
    __syncthreads();
    for (int str = 128; str; str >>= 1) {
        if (threadIdx.x < str) s[threadIdx.x] += s[threadIdx.x + str];
        __syncthreads();
    }
    if (threadIdx.x == 0) out[0] = (float)(s[0] / (double)B);
}

extern "C" void kernel_launch(void* const* d_in, const int* in_sizes, int n_in,
                              void* d_out, int out_size, void* d_ws, size_t ws_size,
                              hipStream_t stream) {
    const float* pred = (const float*)d_in[0];
    const float* bbox = (const float*)d_in[1];
    int B = in_sizes[0] / CELLSZ;
    int nbox = in_sizes[1] / (B * 5);
    if (nbox > MAXBOX) nbox = MAXBOX;
    float* out = (float*)d_out;
    float* partial = (float*)d_ws;

    int nblocks = (B + BPB - 1) / BPB;
    yolo_main<<<nblocks, 256, 0, stream>>>(pred, bbox, partial, B, nbox);
    yolo_reduce<<<1, 256, 0, stream>>>(partial, nblocks, out, B);
}